// Round 10
// baseline (117.472 us; speedup 1.0000x reference)
//
#include <hip/hip_runtime.h>
#include <hip/hip_bf16.h>
#include <math.h>

// Problem constants
#define NSUB   3
#define CFEAT  1024
#define KDIM   3072          // 3 * 32 * 32
#define MDIM   1568          // 32 * 49
#define BATCH  32
#define NK     48            // K-steps of 64 (= 2 frag-KTs of 32)

// Output layout (flat f32): ranking[32,3] | cam 3x2x[32,7,7] | feats 3x[32,1024,7,7]
#define OUT_CAM   96
#define OUT_FEAT  9504
#define FEAT_PER_BRANCH (BATCH * CFEAT * 49)   // 1605632

// Workspace byte offsets.
// A frags: 25*96*4 = 9600 chunks x 64 lanes x 16B
// W frags: 48*96*4 = 18432 chunks x 64 lanes x 16B
#define WS_A      0
#define WS_W      (9600 * 1024)
#define WS_POOLED (WS_W + 18432 * 1024)
#define WS_H      (WS_POOLED + NSUB * BATCH * CFEAT * 4)
#define WS_CAMP   (WS_H + NSUB * BATCH * 512 * 4)

typedef __attribute__((ext_vector_type(8))) short bf16x8;
typedef __attribute__((ext_vector_type(4))) float f32x4;

__device__ __forceinline__ short b16(float f){
    __hip_bfloat16 h = __float2bfloat16(f);
    return *reinterpret_cast<short*>(&h);
}
__device__ __forceinline__ bf16x8 pack8(float4 a, float4 b){
    bf16x8 r;
    r[0]=b16(a.x); r[1]=b16(a.y); r[2]=b16(a.z); r[3]=b16(a.w);
    r[4]=b16(b.x); r[5]=b16(b.y); r[6]=b16(b.z); r[7]=b16(b.w);
    return r;
}

// global -> LDS direct copy, 16B per lane (dest = wave-uniform base + lane*16)
typedef const __attribute__((address_space(1))) void* gas1_t;
typedef __attribute__((address_space(3))) void* las3_t;
__device__ __forceinline__ void gl_lds16(const short* g, char* l){
    __builtin_amdgcn_global_load_lds((gas1_t)g, (las3_t)l, 16, 0, 0);
}

// ---------------------------------------------------------------------------
// Prep into MFMA-fragment layout (unchanged from round 7-9; validated).
// Fragment (16x16x32 bf16 A/B operand): lane l holds row (l&15), k = (l>>4)*8+j.
// Chunk index: A: (MT*96 + KT)*4 + mi ; W: (NTg*96 + KT)*4 + ni  (NTg = i*16+NT).
// Storage: frag[chunk][lane] 16B -> one chunk = 1KB contiguous.
// ---------------------------------------------------------------------------
__global__ __launch_bounds__(256) void prep_frag(
    const float* __restrict__ x, const float* __restrict__ w,
    bf16x8* __restrict__ Af, bf16x8* __restrict__ Wf)
{
    int bid = blockIdx.x, t = threadIdx.x;
    if (bid < 4608) {
        int g = bid * 256 + t;
        int chunk = g >> 6, l = g & 63;
        int ni = chunk & 3, KT = (chunk >> 2) % 96, NTg = chunk / 384;
        int n = NTg * 64 + ni * 16 + (l & 15);       // 0..3071 = flat (i,c)
        int k = KT * 32 + (l >> 4) * 8;
        const float* src = w + (size_t)n * KDIM + k;
        Wf[(size_t)chunk * 64 + l] = pack8(*(const float4*)src, *(const float4*)(src + 4));
    } else {
        int g = (bid - 4608) * 256 + t;
        int chunk = g >> 6, l = g & 63;
        int mi = chunk & 3, KT = (chunk >> 2) % 96, MT = chunk / 384;
        int m  = MT * 64 + mi * 16 + (l & 15);
        int k0 = KT * 32 + (l >> 4) * 8;
        bf16x8 v;
        if (m < MDIM) {
            int b = m / 49, p = m % 49, ph = p / 7, pw = p % 7;
            int ch = k0 >> 10, r = (k0 >> 5) & 31, s = k0 & 31;
            const float* src = x + (((size_t)(b*3 + ch)*224 + ph*32 + r)*224 + pw*32 + s);
            v = pack8(*(const float4*)src, *(const float4*)(src + 4));
        } else {
            v = (bf16x8){0,0,0,0,0,0,0,0};           // pad rows: zero
        }
        Af[(size_t)chunk * 64 + l] = v;
    }
}

// ---------------------------------------------------------------------------
// Conv GEMM bf16 MFMA. Round-3 TLP structure (128x64 block, 4 waves 2x2,
// 624 blocks, 1 barrier per k-step, dbuf) with halved LDS traffic:
//  - A staged via global_load_lds in FRAG layout: each gl_lds writes one 1KB
//    chunk (uniform dest + lane*16, linear, no swizzle needed; rule-21 trivial).
//  - B read global->reg from frag array (1KB coalesced lines, L2-hot),
//    prefetched one full k-step ahead, alternating bgA/bgB (static idx).
// LDS 32KB (2 x 16 chunks) -> 3 blocks/CU; 2496 waves of TLP.
// Block mt=12 half wr=1 reads chunks past Af (lands in Wf: finite, discarded).
// ---------------------------------------------------------------------------
__global__ __launch_bounds__(256, 3) void conv_mfma(
    const bf16x8* __restrict__ Af, const bf16x8* __restrict__ Wf,
    const float* __restrict__ bb, float* __restrict__ out)
{
    __shared__ __align__(16) char lds[32768];   // 2 bufs x 16 chunks x 1KB

    int bid = (int)blockIdx.x;
    bid = (bid & 7) * 78 + (bid >> 3);          // bijective XCD swizzle (624=8*78)
    const int i   = bid / 208;
    const int rem = bid % 208;
    const int nt  = rem / 13, mt = rem % 13;    // mt fastest: B panel L2-hot per XCD

    const int t = threadIdx.x, wv = t >> 6, l = t & 63;
    const int wr = wv >> 1, wc = wv & 1;
    const int lrow = l & 15, lsl = l >> 4;

    // ---- A staging: wave wv owns LDS slots wv*4+q (1KB chunks) ----
    // source chunk(kstep ks) = (2mt + (wv>>1))*384 + ks*8 + (wv&1)*4 + q
    const bf16x8* Ag[4]; int Ad[4];
#pragma unroll
    for (int q = 0; q < 4; ++q) {
        int chunk = (2*mt + (wv >> 1))*384 + (wv & 1)*4 + q;
        Ag[q] = Af + (size_t)chunk * 64 + l;
        Ad[q] = (wv*4 + q) * 1024;
    }

    // ---- B frag pointers: chunk = NTg*384 + ks*8 + kk*4 + (wc*2+ni) ----
    const int NTg = i*16 + nt;
    const bf16x8* Bp[2][2];
#pragma unroll
    for (int ni = 0; ni < 2; ++ni)
#pragma unroll
        for (int kk = 0; kk < 2; ++kk)
            Bp[ni][kk] = Wf + (size_t)(NTg*384 + kk*4 + wc*2 + ni) * 64 + l;

    f32x4 acc[4][2] = {};
    bf16x8 bgA[2][2], bgB[2][2];

    // prologue: stage kstep 0 -> buf0, B(0) -> bgA
#pragma unroll
    for (int q = 0; q < 4; ++q) gl_lds16((const short*)Ag[q], lds + Ad[q]);
#pragma unroll
    for (int ni = 0; ni < 2; ++ni)
#pragma unroll
        for (int kk = 0; kk < 2; ++kk)
            bgA[ni][kk] = *Bp[ni][kk];

    auto COMPUTE = [&](const char* base, bf16x8 (&BG)[2][2]) {
        bf16x8 af[4][2];
#pragma unroll
        for (int kk = 0; kk < 2; ++kk)
#pragma unroll
            for (int mi = 0; mi < 4; ++mi)
                af[mi][kk] = *(const bf16x8*)(base + ((wr*2 + kk)*4 + mi)*1024 + l*16);
        __builtin_amdgcn_s_setprio(1);
#pragma unroll
        for (int kk = 0; kk < 2; ++kk)
#pragma unroll
            for (int mi = 0; mi < 4; ++mi)
#pragma unroll
                for (int ni = 0; ni < 2; ++ni)
                    acc[mi][ni] = __builtin_amdgcn_mfma_f32_16x16x32_bf16(
                        af[mi][kk], BG[ni][kk], acc[mi][ni], 0, 0, 0);
        __builtin_amdgcn_s_setprio(0);
    };

    for (int kt = 0; kt < NK; kt += 2) {
        // even: compute buf0/bgA; prefetch kt+1 -> buf1/bgB
        __syncthreads();
        if (kt + 1 < NK) {
#pragma unroll
            for (int q = 0; q < 4; ++q)
                gl_lds16((const short*)(Ag[q] + (kt+1)*512), lds + 16384 + Ad[q]);
#pragma unroll
            for (int ni = 0; ni < 2; ++ni)
#pragma unroll
                for (int kk = 0; kk < 2; ++kk)
                    bgB[ni][kk] = Bp[ni][kk][(size_t)(kt+1)*512];
        }
        COMPUTE(lds, bgA);
        // odd: compute buf1/bgB; prefetch kt+2 -> buf0/bgA
        __syncthreads();
        if (kt + 2 < NK) {
#pragma unroll
            for (int q = 0; q < 4; ++q)
                gl_lds16((const short*)(Ag[q] + (kt+2)*512), lds + Ad[q]);
#pragma unroll
            for (int ni = 0; ni < 2; ++ni)
#pragma unroll
                for (int kk = 0; kk < 2; ++kk)
                    bgA[ni][kk] = Bp[ni][kk][(size_t)(kt+2)*512];
        }
        COMPUTE(lds + 16384, bgB);
    }

    // epilogue: bias + scatter to feats[i][b][c][p] (round-3 verbatim)
    float* featb = out + OUT_FEAT + (size_t)i * FEAT_PER_BRANCH;
    float bias[2];
#pragma unroll
    for (int ni = 0; ni < 2; ++ni)
        bias[ni] = bb[i*CFEAT + nt*64 + wc*32 + ni*16 + lrow];
#pragma unroll
    for (int mi = 0; mi < 4; ++mi) {
        int mbase = mt*128 + wr*64 + mi*16 + lsl*4;
#pragma unroll
        for (int r = 0; r < 4; ++r) {
            int m = mbase + r;
            if (m >= MDIM) continue;
            int b = m/49, p = m%49;
#pragma unroll
            for (int ni = 0; ni < 2; ++ni) {
                int n = nt*64 + wc*32 + ni*16 + lrow;
                featb[(size_t)(b*CFEAT + n)*49 + p] = acc[mi][ni][r] + bias[ni];
            }
        }
    }
}

// ---------------------------------------------------------------------------
// Pool + partial CAM: 768 blocks (i, b, 128-channel chunk), 128 threads.
// ---------------------------------------------------------------------------
__global__ __launch_bounds__(128) void cam_pool(
    const float* __restrict__ feat, const float* __restrict__ cls_w,
    float* __restrict__ pooled, float* __restrict__ camp)
{
    __shared__ float fs[128][50];
    int bid = blockIdx.x;                  // (i*32+b)*8 + ch
    int i = bid >> 8, b = (bid >> 3) & 31, ch = bid & 7;
    int t = threadIdx.x;
    int c0 = ch * 128;
    const float* f = feat + ((size_t)(i*BATCH + b) * CFEAT + c0) * 49;

    for (int qq = 0; qq < 49; ++qq) {
        int e = qq*128 + t;
        fs[e / 49][e % 49] = f[e];
    }
    __syncthreads();

    {
        float s = 0.f;
#pragma unroll
        for (int k = 0; k < 49; ++k) s += fs[t][k];
        pooled[(size_t)(i*BATCH + b) * CFEAT + c0 + t] = s * (1.f/49.f);
    }

    if (t < 98) {
        int o = t / 49, p = t % 49;
        const float* w = cls_w + (size_t)i * 2 * CFEAT + o * CFEAT + c0;
        float s = 0.f;
        for (int c = 0; c < 128; ++c) s += w[c] * fs[c][p];
        camp[(size_t)bid * 98 + t] = s;
    }
}

// ---------------------------------------------------------------------------
// MLP layer 1 (blocks 0..47) + CAM finalize (blocks 48..84).
// ---------------------------------------------------------------------------
__global__ __launch_bounds__(256) void mlp1_kernel(
    const float* __restrict__ pooled, const float* __restrict__ p1w,
    const float* __restrict__ p1b, float* __restrict__ h,
    const float* __restrict__ camp, float* __restrict__ out_cam)
{
    if (blockIdx.x >= 48) {                 // CAM finalize: sum 8 chunk partials
        int fid = (blockIdx.x - 48) * 256 + threadIdx.x;
        if (fid < NSUB * 2 * MDIM) {
            int io = fid / MDIM, rem = fid % MDIM;
            int b = rem / 49, p = rem % 49;
            int i = io >> 1, o = io & 1;
            float s = 0.f;
#pragma unroll
            for (int c = 0; c < 8; ++c)
                s += camp[(size_t)(((i*BATCH + b)*8) + c) * 98 + o*49 + p];
            out_cam[fid] = fmaxf(s, 0.f);
        }
        return;
    }
    __shared__ float ps[32 * 256];
    int i = blockIdx.x >> 4, jc = blockIdx.x & 15;
    int t = threadIdx.x;
    int j = jc*32 + (t & 31);
    int bg = (t >> 5) * 4;
    float acc[4] = {};
    const float* wrow = p1w + ((size_t)i*512 + j) * CFEAT;
    for (int kc = 0; kc < 4; ++kc) {
        __syncthreads();
#pragma unroll
        for (int qq = 0; qq < 8; ++qq) {
            int f4 = t + qq*256;                 // 0..2047 float4s
            int b = f4 >> 6, k4 = (f4 & 63) * 4;
            *(float4*)&ps[b*256 + k4] =
                *(const float4*)&pooled[((size_t)i*32 + b)*CFEAT + kc*256 + k4];
        }
        __syncthreads();
        const float* wk = wrow + kc*256;
        for (int k = 0; k < 256; k += 4) {
            float4 w4 = *(const float4*)(wk + k);
#pragma unroll
            for (int qq = 0; qq < 4; ++qq) {
                const float* pr = &ps[(bg + qq)*256 + k];  // wave-uniform: broadcast
                acc[qq] += w4.x*pr[0] + w4.y*pr[1] + w4.z*pr[2] + w4.w*pr[3];
            }
        }
    }
    float bias = p1b[i*512 + j];
#pragma unroll
    for (int qq = 0; qq < 4; ++qq)
        h[((size_t)i*32 + bg + qq)*512 + j] = fmaxf(acc[qq] + bias, 0.f);
}

// ---------------------------------------------------------------------------
// MLP layer 2 + softmax[:,1]: block per branch.
// ---------------------------------------------------------------------------
__global__ void mlp2_kernel(const float* __restrict__ h, const float* __restrict__ p2w,
                            const float* __restrict__ p2b, float* __restrict__ out)
{
    __shared__ float part[256];
    int i = blockIdx.x, t = threadIdx.x;
    int b = t & 31, kc = t >> 5;                 // kc 0..7, 64 k each
    const float* hv = h + ((size_t)i*32 + b)*512 + kc*64;
    const float* w0 = p2w + (size_t)i*1024 + kc*64;
    const float* w1 = w0 + 512;
    float s = 0.f;
    for (int k = 0; k < 64; ++k) s += hv[k] * (w1[k] - w0[k]);
    part[t] = s;
    __syncthreads();
    if (t < 32) {
        float d = 0.f;
#pragma unroll
        for (int qq = 0; qq < 8; ++qq) d += part[qq*32 + t];
        d += p2b[i*2 + 1] - p2b[i*2 + 0];
        out[b*NSUB + i] = 1.f / (1.f + expf(-d));
    }
}

// ---------------------------------------------------------------------------
extern "C" void kernel_launch(void* const* d_in, const int* in_sizes, int n_in,
                              void* d_out, int out_size, void* d_ws, size_t ws_size,
                              hipStream_t stream)
{
    const float* x    = (const float*)d_in[0];
    const float* Wb   = (const float*)d_in[1];
    const float* bbp  = (const float*)d_in[2];
    const float* p1w  = (const float*)d_in[3];
    const float* p1b  = (const float*)d_in[4];
    const float* p2w  = (const float*)d_in[5];
    const float* p2b  = (const float*)d_in[6];
    const float* clsw = (const float*)d_in[7];
    float* out = (float*)d_out;

    char* ws = (char*)d_ws;
    bf16x8* Af    = (bf16x8*)(ws + WS_A);
    bf16x8* Wf    = (bf16x8*)(ws + WS_W);
    float* pooled = (float*)(ws + WS_POOLED);
    float* hbuf   = (float*)(ws + WS_H);
    float* camp   = (float*)(ws + WS_CAMP);

    prep_frag<<<4608 + 2400, 256, 0, stream>>>(x, Wb, Af, Wf);
    conv_mfma<<<624, 256, 0, stream>>>(Af, Wf, bbp, out);
    cam_pool<<<NSUB*BATCH*8, 128, 0, stream>>>(out + OUT_FEAT, clsw, pooled, camp);
    mlp1_kernel<<<48 + 37, 256, 0, stream>>>(pooled, p1w, p1b, hbuf, camp, out + OUT_CAM);
    mlp2_kernel<<<NSUB, 256, 0, stream>>>(hbuf, p2w, p2b, out);
}

// Round 11
// 115.760 us; speedup vs baseline: 1.0148x; 1.0148x over previous
//
#include <hip/hip_runtime.h>
#include <hip/hip_bf16.h>
#include <math.h>

// Problem constants
#define NSUB   3
#define CFEAT  1024
#define KDIM   3072          // 3 * 32 * 32
#define MDIM   1568          // 32 * 49
#define BATCH  32
#define NK     48            // K-steps of 64 (= 2 frag-KTs of 32)

// Output layout (flat f32): ranking[32,3] | cam 3x2x[32,7,7] | feats 3x[32,1024,7,7]
#define OUT_CAM   96
#define OUT_FEAT  9504
#define FEAT_PER_BRANCH (BATCH * CFEAT * 49)   // 1605632

// Workspace byte offsets.
// A frags: 25*96*4 = 9600 chunks x 64 lanes x 16B
// W frags: 48*96*4 = 18432 chunks x 64 lanes x 16B
#define WS_A      0
#define WS_W      (9600 * 1024)
#define WS_POOLED (WS_W + 18432 * 1024)
#define WS_H      (WS_POOLED + NSUB * BATCH * CFEAT * 4)
#define WS_CAMP   (WS_H + NSUB * BATCH * 512 * 4)

typedef __attribute__((ext_vector_type(8))) short bf16x8;
typedef __attribute__((ext_vector_type(4))) float f32x4;

__device__ __forceinline__ short b16(float f){
    __hip_bfloat16 h = __float2bfloat16(f);
    return *reinterpret_cast<short*>(&h);
}
__device__ __forceinline__ bf16x8 pack8(float4 a, float4 b){
    bf16x8 r;
    r[0]=b16(a.x); r[1]=b16(a.y); r[2]=b16(a.z); r[3]=b16(a.w);
    r[4]=b16(b.x); r[5]=b16(b.y); r[6]=b16(b.z); r[7]=b16(b.w);
    return r;
}

// global -> LDS direct copy, 16B per lane (dest = wave-uniform base + lane*16)
typedef const __attribute__((address_space(1))) void* gas1_t;
typedef __attribute__((address_space(3))) void* las3_t;
__device__ __forceinline__ void gl_lds16(const short* g, char* l){
    __builtin_amdgcn_global_load_lds((gas1_t)g, (las3_t)l, 16, 0, 0);
}

// ---------------------------------------------------------------------------
// Prep into MFMA-fragment layout (unchanged; validated rounds 7-10).
// Fragment (16x16x32 bf16 A/B operand): lane l holds row (l&15), k = (l>>4)*8+j.
// Chunk index: A: (MT*96 + KT)*4 + mi ; W: (NTg*96 + KT)*4 + ni  (NTg = i*16+NT).
// ---------------------------------------------------------------------------
__global__ __launch_bounds__(256) void prep_frag(
    const float* __restrict__ x, const float* __restrict__ w,
    bf16x8* __restrict__ Af, bf16x8* __restrict__ Wf)
{
    int bid = blockIdx.x, t = threadIdx.x;
    if (bid < 4608) {
        int g = bid * 256 + t;
        int chunk = g >> 6, l = g & 63;
        int ni = chunk & 3, KT = (chunk >> 2) % 96, NTg = chunk / 384;
        int n = NTg * 64 + ni * 16 + (l & 15);       // 0..3071 = flat (i,c)
        int k = KT * 32 + (l >> 4) * 8;
        const float* src = w + (size_t)n * KDIM + k;
        Wf[(size_t)chunk * 64 + l] = pack8(*(const float4*)src, *(const float4*)(src + 4));
    } else {
        int g = (bid - 4608) * 256 + t;
        int chunk = g >> 6, l = g & 63;
        int mi = chunk & 3, KT = (chunk >> 2) % 96, MT = chunk / 384;
        int m  = MT * 64 + mi * 16 + (l & 15);
        int k0 = KT * 32 + (l >> 4) * 8;
        bf16x8 v;
        if (m < MDIM) {
            int b = m / 49, p = m % 49, ph = p / 7, pw = p % 7;
            int ch = k0 >> 10, r = (k0 >> 5) & 31, s = k0 & 31;
            const float* src = x + (((size_t)(b*3 + ch)*224 + ph*32 + r)*224 + pw*32 + s);
            v = pack8(*(const float4*)src, *(const float4*)(src + 4));
        } else {
            v = (bf16x8){0,0,0,0,0,0,0,0};           // pad rows: zero
        }
        Af[(size_t)chunk * 64 + l] = v;
    }
}

// ---------------------------------------------------------------------------
// Conv GEMM bf16 MFMA. Body identical to round 10 (passed). ONLY the block
// mapping changes: 2-level XCD-aware permutation to cut L3 traffic ~4x.
//   xcd = bid & 7 (HW round-robins XCDs by blockIdx)
//   XCD x owns B-panels ntg in [6x, 6x+6): working set 2.3 MB -> B L2-RESIDENT
//   within XCD: mt-major, k6 inner -> A panel (768 KB) L2-hot for 6 blocks
// L3 reads: A 13x768KBx8 = 80 MB + B 18.9 MB (vs ~480 MB for all prior
// variants, which all measured 50-59 us = the shared ~9.6 TB/s L3 wall).
// ---------------------------------------------------------------------------
__global__ __launch_bounds__(256, 3) void conv_mfma(
    const bf16x8* __restrict__ Af, const bf16x8* __restrict__ Wf,
    const float* __restrict__ bb, float* __restrict__ out)
{
    __shared__ __align__(16) char lds[32768];   // 2 bufs x 16 chunks x 1KB

    const int d    = (int)blockIdx.x;
    const int xcd  = d & 7;
    const int s    = d >> 3;                    // 0..77 within XCD
    const int mt   = s / 6;                     // 13 mt, A panel hot across 6
    const int ntg  = xcd * 6 + (s % 6);         // 6 B panels per XCD, L2-resident
    const int i    = ntg >> 4;
    const int nt   = ntg & 15;

    const int t = threadIdx.x, wv = t >> 6, l = t & 63;
    const int wr = wv >> 1, wc = wv & 1;
    const int lrow = l & 15, lsl = l >> 4;

    // ---- A staging: wave wv owns LDS slots wv*4+q (1KB chunks) ----
    const bf16x8* Ag[4]; int Ad[4];
#pragma unroll
    for (int q = 0; q < 4; ++q) {
        int chunk = (2*mt + (wv >> 1))*384 + (wv & 1)*4 + q;
        Ag[q] = Af + (size_t)chunk * 64 + l;
        Ad[q] = (wv*4 + q) * 1024;
    }

    // ---- B frag pointers: chunk = NTg*384 + ks*8 + kk*4 + (wc*2+ni) ----
    const int NTg = i*16 + nt;
    const bf16x8* Bp[2][2];
#pragma unroll
    for (int ni = 0; ni < 2; ++ni)
#pragma unroll
        for (int kk = 0; kk < 2; ++kk)
            Bp[ni][kk] = Wf + (size_t)(NTg*384 + kk*4 + wc*2 + ni) * 64 + l;

    f32x4 acc[4][2] = {};
    bf16x8 bgA[2][2], bgB[2][2];

    // prologue: stage kstep 0 -> buf0, B(0) -> bgA
#pragma unroll
    for (int q = 0; q < 4; ++q) gl_lds16((const short*)Ag[q], lds + Ad[q]);
#pragma unroll
    for (int ni = 0; ni < 2; ++ni)
#pragma unroll
        for (int kk = 0; kk < 2; ++kk)
            bgA[ni][kk] = *Bp[ni][kk];

    auto COMPUTE = [&](const char* base, bf16x8 (&BG)[2][2]) {
        bf16x8 af[4][2];
#pragma unroll
        for (int kk = 0; kk < 2; ++kk)
#pragma unroll
            for (int mi = 0; mi < 4; ++mi)
                af[mi][kk] = *(const bf16x8*)(base + ((wr*2 + kk)*4 + mi)*1024 + l*16);
        __builtin_amdgcn_s_setprio(1);
#pragma unroll
        for (int kk = 0; kk < 2; ++kk)
#pragma unroll
            for (int mi = 0; mi < 4; ++mi)
#pragma unroll
                for (int ni = 0; ni < 2; ++ni)
                    acc[mi][ni] = __builtin_amdgcn_mfma_f32_16x16x32_bf16(
                        af[mi][kk], BG[ni][kk], acc[mi][ni], 0, 0, 0);
        __builtin_amdgcn_s_setprio(0);
    };

    for (int kt = 0; kt < NK; kt += 2) {
        // even: compute buf0/bgA; prefetch kt+1 -> buf1/bgB
        __syncthreads();
        if (kt + 1 < NK) {
#pragma unroll
            for (int q = 0; q < 4; ++q)
                gl_lds16((const short*)(Ag[q] + (kt+1)*512), lds + 16384 + Ad[q]);
#pragma unroll
            for (int ni = 0; ni < 2; ++ni)
#pragma unroll
                for (int kk = 0; kk < 2; ++kk)
                    bgB[ni][kk] = Bp[ni][kk][(size_t)(kt+1)*512];
        }
        COMPUTE(lds, bgA);
        // odd: compute buf1/bgB; prefetch kt+2 -> buf0/bgA
        __syncthreads();
        if (kt + 2 < NK) {
#pragma unroll
            for (int q = 0; q < 4; ++q)
                gl_lds16((const short*)(Ag[q] + (kt+2)*512), lds + Ad[q]);
#pragma unroll
            for (int ni = 0; ni < 2; ++ni)
#pragma unroll
                for (int kk = 0; kk < 2; ++kk)
                    bgA[ni][kk] = Bp[ni][kk][(size_t)(kt+2)*512];
        }
        COMPUTE(lds + 16384, bgB);
    }

    // epilogue: bias + scatter to feats[i][b][c][p]
    float* featb = out + OUT_FEAT + (size_t)i * FEAT_PER_BRANCH;
    float bias[2];
#pragma unroll
    for (int ni = 0; ni < 2; ++ni)
        bias[ni] = bb[i*CFEAT + nt*64 + wc*32 + ni*16 + lrow];
#pragma unroll
    for (int mi = 0; mi < 4; ++mi) {
        int mbase = mt*128 + wr*64 + mi*16 + lsl*4;
#pragma unroll
        for (int r = 0; r < 4; ++r) {
            int m = mbase + r;
            if (m >= MDIM) continue;
            int b = m/49, p = m%49;
#pragma unroll
            for (int ni = 0; ni < 2; ++ni) {
                int n = nt*64 + wc*32 + ni*16 + lrow;
                featb[(size_t)(b*CFEAT + n)*49 + p] = acc[mi][ni][r] + bias[ni];
            }
        }
    }
}

// ---------------------------------------------------------------------------
// Pool + partial CAM: 768 blocks (i, b, 128-channel chunk), 128 threads.
// ---------------------------------------------------------------------------
__global__ __launch_bounds__(128) void cam_pool(
    const float* __restrict__ feat, const float* __restrict__ cls_w,
    float* __restrict__ pooled, float* __restrict__ camp)
{
    __shared__ float fs[128][50];
    int bid = blockIdx.x;                  // (i*32+b)*8 + ch
    int i = bid >> 8, b = (bid >> 3) & 31, ch = bid & 7;
    int t = threadIdx.x;
    int c0 = ch * 128;
    const float* f = feat + ((size_t)(i*BATCH + b) * CFEAT + c0) * 49;

    for (int qq = 0; qq < 49; ++qq) {
        int e = qq*128 + t;
        fs[e / 49][e % 49] = f[e];
    }
    __syncthreads();

    {
        float s = 0.f;
#pragma unroll
        for (int k = 0; k < 49; ++k) s += fs[t][k];
        pooled[(size_t)(i*BATCH + b) * CFEAT + c0 + t] = s * (1.f/49.f);
    }

    if (t < 98) {
        int o = t / 49, p = t % 49;
        const float* w = cls_w + (size_t)i * 2 * CFEAT + o * CFEAT + c0;
        float s = 0.f;
        for (int c = 0; c < 128; ++c) s += w[c] * fs[c][p];
        camp[(size_t)bid * 98 + t] = s;
    }
}

// ---------------------------------------------------------------------------
// MLP layer 1 (blocks 0..47) + CAM finalize (blocks 48..84).
// ---------------------------------------------------------------------------
__global__ __launch_bounds__(256) void mlp1_kernel(
    const float* __restrict__ pooled, const float* __restrict__ p1w,
    const float* __restrict__ p1b, float* __restrict__ h,
    const float* __restrict__ camp, float* __restrict__ out_cam)
{
    if (blockIdx.x >= 48) {                 // CAM finalize: sum 8 chunk partials
        int fid = (blockIdx.x - 48) * 256 + threadIdx.x;
        if (fid < NSUB * 2 * MDIM) {
            int io = fid / MDIM, rem = fid % MDIM;
            int b = rem / 49, p = rem % 49;
            int i = io >> 1, o = io & 1;
            float s = 0.f;
#pragma unroll
            for (int c = 0; c < 8; ++c)
                s += camp[(size_t)(((i*BATCH + b)*8) + c) * 98 + o*49 + p];
            out_cam[fid] = fmaxf(s, 0.f);
        }
        return;
    }
    __shared__ float ps[32 * 256];
    int i = blockIdx.x >> 4, jc = blockIdx.x & 15;
    int t = threadIdx.x;
    int j = jc*32 + (t & 31);
    int bg = (t >> 5) * 4;
    float acc[4] = {};
    const float* wrow = p1w + ((size_t)i*512 + j) * CFEAT;
    for (int kc = 0; kc < 4; ++kc) {
        __syncthreads();
#pragma unroll
        for (int qq = 0; qq < 8; ++qq) {
            int f4 = t + qq*256;                 // 0..2047 float4s
            int b = f4 >> 6, k4 = (f4 & 63) * 4;
            *(float4*)&ps[b*256 + k4] =
                *(const float4*)&pooled[((size_t)i*32 + b)*CFEAT + kc*256 + k4];
        }
        __syncthreads();
        const float* wk = wrow + kc*256;
        for (int k = 0; k < 256; k += 4) {
            float4 w4 = *(const float4*)(wk + k);
#pragma unroll
            for (int qq = 0; qq < 4; ++qq) {
                const float* pr = &ps[(bg + qq)*256 + k];  // wave-uniform: broadcast
                acc[qq] += w4.x*pr[0] + w4.y*pr[1] + w4.z*pr[2] + w4.w*pr[3];
            }
        }
    }
    float bias = p1b[i*512 + j];
#pragma unroll
    for (int qq = 0; qq < 4; ++qq)
        h[((size_t)i*32 + bg + qq)*512 + j] = fmaxf(acc[qq] + bias, 0.f);
}

// ---------------------------------------------------------------------------
// MLP layer 2 + softmax[:,1]: block per branch.
// ---------------------------------------------------------------------------
__global__ void mlp2_kernel(const float* __restrict__ h, const float* __restrict__ p2w,
                            const float* __restrict__ p2b, float* __restrict__ out)
{
    __shared__ float part[256];
    int i = blockIdx.x, t = threadIdx.x;
    int b = t & 31, kc = t >> 5;                 // kc 0..7, 64 k each
    const float* hv = h + ((size_t)i*32 + b)*512 + kc*64;
    const float* w0 = p2w + (size_t)i*1024 + kc*64;
    const float* w1 = w0 + 512;
    float s = 0.f;
    for (int k = 0; k < 64; ++k) s += hv[k] * (w1[k] - w0[k]);
    part[t] = s;
    __syncthreads();
    if (t < 32) {
        float d = 0.f;
#pragma unroll
        for (int qq = 0; qq < 8; ++qq) d += part[qq*32 + t];
        d += p2b[i*2 + 1] - p2b[i*2 + 0];
        out[b*NSUB + i] = 1.f / (1.f + expf(-d));
    }
}

// ---------------------------------------------------------------------------
extern "C" void kernel_launch(void* const* d_in, const int* in_sizes, int n_in,
                              void* d_out, int out_size, void* d_ws, size_t ws_size,
                              hipStream_t stream)
{
    const float* x    = (const float*)d_in[0];
    const float* Wb   = (const float*)d_in[1];
    const float* bbp  = (const float*)d_in[2];
    const float* p1w  = (const float*)d_in[3];
    const float* p1b  = (const float*)d_in[4];
    const float* p2w  = (const float*)d_in[5];
    const float* p2b  = (const float*)d_in[6];
    const float* clsw = (const float*)d_in[7];
    float* out = (float*)d_out;

    char* ws = (char*)d_ws;
    bf16x8* Af    = (bf16x8*)(ws + WS_A);
    bf16x8* Wf    = (bf16x8*)(ws + WS_W);
    float* pooled = (float*)(ws + WS_POOLED);
    float* hbuf   = (float*)(ws + WS_H);
    float* camp   = (float*)(ws + WS_CAMP);

    prep_frag<<<4608 + 2400, 256, 0, stream>>>(x, Wb, Af, Wf);
    conv_mfma<<<624, 256, 0, stream>>>(Af, Wf, bbp, out);
    cam_pool<<<NSUB*BATCH*8, 128, 0, stream>>>(out + OUT_FEAT, clsw, pooled, camp);
    mlp1_kernel<<<48 + 37, 256, 0, stream>>>(pooled, p1w, p1b, hbuf, camp, out + OUT_CAM);
    mlp2_kernel<<<NSUB, 256, 0, stream>>>(hbuf, p2w, p2b, out);
}